// Round 10
// baseline (755.238 us; speedup 1.0000x reference)
//
#include <hip/hip_runtime.h>
#include <hip/hip_cooperative_groups.h>

namespace cg = cooperative_groups;

#define N_NODES 50000
#define N_EDGES 800000
#define NF 128
#define BN_EPS 1e-5f
#define G_ROWS 32
#define GBLOCKS ((N_NODES + G_ROWS - 1) / G_ROWS)   // 1563
#define NB 1568   // padded partials pitch (>= GBLOCKS, mult of 32)
#define SCAN_BLOCKS ((N_NODES + 255) / 256)  // 196
#define AP 136  // bf16 A-tile pitch (shorts); 272B rows, 16B aligned
#define HP 132  // fp32 H-tile pitch
#define COOP_BLOCKS 1024

typedef __attribute__((ext_vector_type(8))) short short8;
typedef __attribute__((ext_vector_type(4))) float f32x4;

__device__ __forceinline__ unsigned short f2bf(float f) {
    union { float f; unsigned int i; } v; v.f = f;
    unsigned int r = (v.i + 0x7fffu + ((v.i >> 16) & 1u)) >> 16;
    return (unsigned short)r;
}
__device__ __forceinline__ float bf2f(unsigned short u) {
    union { unsigned int i; float f; } v; v.i = ((unsigned int)u) << 16; return v.f;
}
__device__ __forceinline__ float bflo(unsigned int u) { return bf2f((unsigned short)(u & 0xffffu)); }
__device__ __forceinline__ float bfhi(unsigned int u) { return bf2f((unsigned short)(u >> 16)); }

#define SETUP_C (N_NODES * NF / 4)
#define SETUP_P (128 * 128)

// ============ Cooperative: setup + CSR build in one dispatch ============
__global__ __launch_bounds__(256) void build_coop(
    const float* __restrict__ x, unsigned short* __restrict__ xb,
    const float* __restrict__ W1, const float* __restrict__ W2,
    unsigned short* __restrict__ Wb1, unsigned short* __restrict__ Wb2,
    const int* __restrict__ ei, int* __restrict__ counts,
    int* __restrict__ rank, int* __restrict__ partials,
    int* __restrict__ rowptr, int* __restrict__ ssrc) {
    cg::grid_group grid = cg::this_grid();
    __shared__ int sh[256];
    int t = threadIdx.x;
    int gtid = blockIdx.x * 256 + t;
    int gstride = gridDim.x * 256;

    // Phase 0: x->bf16, W->bf16, zero counts.
    for (int i = gtid; i < SETUP_C; i += gstride) {
        float4 v = ((const float4*)x)[i];
        ushort4 u;
        u.x = f2bf(v.x); u.y = f2bf(v.y); u.z = f2bf(v.z); u.w = f2bf(v.w);
        ((ushort4*)xb)[i] = u;
    }
    for (int i = gtid; i < SETUP_P; i += gstride) {
        Wb1[i] = f2bf(W1[i]);
        Wb2[i] = f2bf(W2[i]);
    }
    for (int i = gtid; i < N_NODES; i += gstride) counts[i] = 0;
    grid.sync();

    // Phase 1: histogram + per-edge rank within dst segment.
    for (int e = gtid; e < N_EDGES; e += gstride)
        rank[e] = atomicAdd(&counts[ei[N_EDGES + e]], 1);
    grid.sync();

    // Phase 2: per-256-chunk reduction -> partials.
    if (blockIdx.x < SCAN_BLOCKS) {
        int i = blockIdx.x * 256 + t;
        sh[t] = (i < N_NODES) ? counts[i] : 0;
        __syncthreads();
        for (int off = 128; off > 0; off >>= 1) {
            if (t < off) sh[t] += sh[t + off];
            __syncthreads();
        }
        if (t == 0) partials[blockIdx.x] = sh[0];
    }
    grid.sync();

    // Phase 3: exclusive scan of partials (block 0).
    if (blockIdx.x == 0) {
        int v = (t < SCAN_BLOCKS) ? partials[t] : 0;
        sh[t] = v;
        __syncthreads();
        for (int off = 1; off < 256; off <<= 1) {
            int u = (t >= off) ? sh[t - off] : 0;
            __syncthreads();
            sh[t] += u;
            __syncthreads();
        }
        if (t < SCAN_BLOCKS) partials[t] = sh[t] - v;
    }
    grid.sync();

    // Phase 4: block-local scan + offset -> rowptr.
    if (blockIdx.x < SCAN_BLOCKS) {
        int i = blockIdx.x * 256 + t;
        int v = (i < N_NODES) ? counts[i] : 0;
        sh[t] = v;
        __syncthreads();
        for (int off = 1; off < 256; off <<= 1) {
            int u = (t >= off) ? sh[t - off] : 0;
            __syncthreads();
            sh[t] += u;
            __syncthreads();
        }
        int excl = partials[blockIdx.x] + sh[t] - v;
        if (i < N_NODES) rowptr[i] = excl;
        if (i == 0) rowptr[N_NODES] = N_EDGES;
    }
    grid.sync();

    // Phase 5: atomic-free fill.
    for (int e = gtid; e < N_EDGES; e += gstride) {
        int dst = ei[N_EDGES + e];
        ssrc[rowptr[dst] + rank[e]] = ei[e];
    }
}

// ============ Classic CSR-build kernels (fallback if no coop) ============
__global__ void setup_kernel(const float* __restrict__ x, unsigned short* __restrict__ xb,
                             const float* __restrict__ W1, const float* __restrict__ W2,
                             unsigned short* __restrict__ Wb1, unsigned short* __restrict__ Wb2,
                             int* __restrict__ counts, float* __restrict__ stats,
                             int do_convert) {
    int i = blockIdx.x * blockDim.x + threadIdx.x;
    int off = do_convert ? 0 : SETUP_C;
    i += off;
    if (i < SETUP_C) {
        float4 v = ((const float4*)x)[i];
        ushort4 u;
        u.x = f2bf(v.x); u.y = f2bf(v.y); u.z = f2bf(v.z); u.w = f2bf(v.w);
        ((ushort4*)xb)[i] = u;
    } else if (i < SETUP_C + SETUP_P) {
        int j = i - SETUP_C;
        Wb1[j] = f2bf(W1[j]);
        Wb2[j] = f2bf(W2[j]);
    } else if (i < SETUP_C + SETUP_P + N_NODES) {
        counts[i - SETUP_C - SETUP_P] = 0;
    } else if (i < SETUP_C + SETUP_P + N_NODES + 256) {
        stats[i - SETUP_C - SETUP_P - N_NODES] = 0.0f;
    }
}

__global__ void hist_kernel(const int* __restrict__ ei, int* __restrict__ counts,
                            int* __restrict__ rank) {
    int t = blockIdx.x * blockDim.x + threadIdx.x;
    if (t < N_EDGES) rank[t] = atomicAdd(&counts[ei[N_EDGES + t]], 1);
}

__global__ __launch_bounds__(256) void scan_reduce(const int* __restrict__ counts,
                                                   int* __restrict__ partials) {
    __shared__ int red[256];
    int t = threadIdx.x;
    int i = blockIdx.x * 256 + t;
    red[t] = (i < N_NODES) ? counts[i] : 0;
    __syncthreads();
    for (int off = 128; off > 0; off >>= 1) {
        if (t < off) red[t] += red[t + off];
        __syncthreads();
    }
    if (t == 0) partials[blockIdx.x] = red[0];
}

__global__ __launch_bounds__(256) void scan_partials2(int* __restrict__ partials) {
    __shared__ int s[256];
    int t = threadIdx.x;
    int v = (t < SCAN_BLOCKS) ? partials[t] : 0;
    s[t] = v;
    __syncthreads();
    for (int off = 1; off < 256; off <<= 1) {
        int u = (t >= off) ? s[t - off] : 0;
        __syncthreads();
        s[t] += u;
        __syncthreads();
    }
    if (t < SCAN_BLOCKS) partials[t] = s[t] - v;
}

__global__ __launch_bounds__(256) void scan_apply(const int* __restrict__ counts,
                                                  const int* __restrict__ partials,
                                                  int* __restrict__ rowptr) {
    __shared__ int s[256];
    int t = threadIdx.x;
    int i = blockIdx.x * 256 + t;
    int v = (i < N_NODES) ? counts[i] : 0;
    s[t] = v;
    __syncthreads();
    for (int off = 1; off < 256; off <<= 1) {
        int u = (t >= off) ? s[t - off] : 0;
        __syncthreads();
        s[t] += u;
        __syncthreads();
    }
    int excl = partials[blockIdx.x] + s[t] - v;
    if (i < N_NODES) rowptr[i] = excl;
    if (i == 0) rowptr[N_NODES] = N_EDGES;
}

__global__ void fill_kernel(const int* __restrict__ ei,
                            const int* __restrict__ rowptr,
                            const int* __restrict__ rank,
                            int* __restrict__ ssrc) {
    int t = blockIdx.x * blockDim.x + threadIdx.x;
    if (t < N_EDGES) {
        int dst = ei[N_EDGES + t];
        ssrc[rowptr[dst] + rank[t]] = ei[t];
    }
}

// -------- Gather (bf16, pairwise): one wave per node, 2 neighbors/load-inst --
// Lane l: half=l>>5 picks neighbor e+half; fl=l&31 picks feature quad (8B).
// Halves combined with shfl_xor(32) at the end.
__global__ __launch_bounds__(256) void gather_bf16(const unsigned short* __restrict__ xb,
                                                   const int* __restrict__ rowptr,
                                                   const int* __restrict__ ssrc,
                                                   unsigned short* __restrict__ buf) {
    int node = (blockIdx.x * blockDim.x + threadIdx.x) >> 6;
    int lane = threadIdx.x & 63;
    if (node >= N_NODES) return;
    int half = lane >> 5;
    int fl = lane & 31;
    const uint2* x4 = (const uint2*)xb;  // 8 B = 4 bf16 features

    float a0 = 0.f, a1 = 0.f, a2 = 0.f, a3 = 0.f;
    if (half == 0) {
        uint2 u = x4[(size_t)node * 32 + fl];
        a0 = bflo(u.x); a1 = bfhi(u.x); a2 = bflo(u.y); a3 = bfhi(u.y);
    }
    int beg = rowptr[node], end = rowptr[node + 1];
    int e = beg;
    for (; e + 3 < end; e += 4) {  // 4 neighbors per iter, 2 loads/lane
        int sA = ssrc[e + half];
        int sB = ssrc[e + 2 + half];
        uint2 uA = x4[(size_t)sA * 32 + fl];
        uint2 uB = x4[(size_t)sB * 32 + fl];
        a0 += bflo(uA.x) + bflo(uB.x);
        a1 += bfhi(uA.x) + bfhi(uB.x);
        a2 += bflo(uA.y) + bflo(uB.y);
        a3 += bfhi(uA.y) + bfhi(uB.y);
    }
    for (; e + 1 < end; e += 2) {  // 2 neighbors, 1 load/lane
        int s = ssrc[e + half];
        uint2 u = x4[(size_t)s * 32 + fl];
        a0 += bflo(u.x); a1 += bfhi(u.x);
        a2 += bflo(u.y); a3 += bfhi(u.y);
    }
    if (e < end && half == 0) {    // odd tail: lower half only
        int s = ssrc[e];
        uint2 u = x4[(size_t)s * 32 + fl];
        a0 += bflo(u.x); a1 += bfhi(u.x);
        a2 += bflo(u.y); a3 += bfhi(u.y);
    }
    a0 += __shfl_xor(a0, 32);
    a1 += __shfl_xor(a1, 32);
    a2 += __shfl_xor(a2, 32);
    a3 += __shfl_xor(a3, 32);
    if (half == 0) {
        uint2 o;
        o.x = ((unsigned int)f2bf(a1) << 16) | (unsigned int)f2bf(a0);
        o.y = ((unsigned int)f2bf(a3) << 16) | (unsigned int)f2bf(a2);
        ((uint2*)buf)[(size_t)node * 32 + fl] = o;
    }
}

// ------- GEMM1 (bf16 in-place): buf = bf16(relu(buf @ W1^T + b1)) ------------
__global__ __launch_bounds__(256) void gemm1_bf16(
    unsigned short* __restrict__ buf,
    const unsigned short* __restrict__ Wb,
    const float* __restrict__ b1,
    float* __restrict__ P) {
    __shared__ unsigned short At[G_ROWS][AP];
    __shared__ float Ht[G_ROWS][HP];

    int t = threadIdx.x;
    int base = blockIdx.x * G_ROWS;
    int nrows = N_NODES - base; if (nrows > G_ROWS) nrows = G_ROWS;

    for (int i = t; i < G_ROWS * 16; i += 256) {
        int r = i >> 4, c8 = i & 15;
        uint4 v = make_uint4(0u, 0u, 0u, 0u);
        if (r < nrows) v = ((const uint4*)(buf + (size_t)(base + r) * NF))[c8];
        *((uint4*)&At[r][c8 * 8]) = v;
    }
    __syncthreads();

    int wave = t >> 6, lane = t & 63;
    int m0 = (wave & 1) * 16;
    int n0 = (wave >> 1) * 64;
    int l15 = lane & 15, q = lane >> 4;

    f32x4 acc[4];
#pragma unroll
    for (int i = 0; i < 4; i++) acc[i] = (f32x4){0.f, 0.f, 0.f, 0.f};

#pragma unroll
    for (int kc = 0; kc < 4; kc++) {
        short8 a = *((const short8*)&At[m0 + l15][kc * 32 + q * 8]);
#pragma unroll
        for (int tile = 0; tile < 4; tile++) {
            short8 b = *((const short8*)(Wb + (size_t)(n0 + 16 * tile + l15) * 128 + kc * 32 + q * 8));
            acc[tile] = __builtin_amdgcn_mfma_f32_16x16x32_bf16(a, b, acc[tile], 0, 0, 0);
        }
    }

#pragma unroll
    for (int tile = 0; tile < 4; tile++) {
        int col = n0 + 16 * tile + l15;
        float bias = b1[col];
#pragma unroll
        for (int reg = 0; reg < 4; reg++) {
            int row = q * 4 + reg;
            Ht[m0 + row][col] = fmaxf(acc[tile][reg] + bias, 0.f);
        }
    }
    __syncthreads();

    for (int i = t; i < G_ROWS * 32; i += 256) {
        int r = i >> 5, c4 = i & 31;
        int row = base + r;
        if (row < N_NODES) {
            float4 v = *((const float4*)&Ht[r][c4 * 4]);
            ushort4 u;
            u.x = f2bf(v.x); u.y = f2bf(v.y); u.z = f2bf(v.z); u.w = f2bf(v.w);
            *((ushort4*)(buf + (size_t)row * NF + c4 * 4)) = u;
        }
    }

    {
        int f = t & 127;
        bool issq = (t >= 128);
        float s = 0.f;
        for (int r = 0; r < nrows; r++) {
            float v = Ht[r][f];
            s += issq ? v * v : v;
        }
        P[(size_t)t * NB + blockIdx.x] = s;
    }
}

// ------- BN reduce + fold (no atomics) ---------------------------------------
__global__ __launch_bounds__(256) void bn_reduce(const float* __restrict__ P,
                                                 const float* __restrict__ gamma,
                                                 const float* __restrict__ beta,
                                                 float* __restrict__ ab) {
    __shared__ float s1[256], s2[256];
    int f = blockIdx.x;
    int j = threadIdx.x;
    float a = 0.f, b = 0.f;
    for (int k = j; k < GBLOCKS; k += 256) {
        a += P[(size_t)f * NB + k];
        b += P[(size_t)(128 + f) * NB + k];
    }
    s1[j] = a; s2[j] = b;
    __syncthreads();
    for (int off = 128; off > 0; off >>= 1) {
        if (j < off) { s1[j] += s1[j + off]; s2[j] += s2[j + off]; }
        __syncthreads();
    }
    if (j == 0) {
        float mean = s1[0] * (1.0f / N_NODES);
        float var = s2[0] * (1.0f / N_NODES) - mean * mean;
        float rstd = rsqrtf(var + BN_EPS);
        float aa = gamma[f] * rstd;
        float cc = beta[f] - mean * aa;
        ab[f] = aa;
        ab[128 + f] = cc;
    }
}

// -------- GEMM2 (bf16 in, fp32 out) ------------------------------------------
__global__ __launch_bounds__(256) void gemm2_bf16(
    const unsigned short* __restrict__ buf,
    const unsigned short* __restrict__ Wb,
    const float* __restrict__ b2,
    const float* __restrict__ ab,
    float* __restrict__ out) {
    __shared__ unsigned short At[G_ROWS][AP];
    __shared__ float Ht[G_ROWS][HP];

    int t = threadIdx.x;
    int base = blockIdx.x * G_ROWS;
    int nrows = N_NODES - base; if (nrows > G_ROWS) nrows = G_ROWS;

    for (int i = t; i < G_ROWS * 32; i += 256) {
        int r = i >> 5, c4 = i & 31;
        ushort4 u = make_ushort4(0, 0, 0, 0);
        if (r < nrows) {
            ushort4 hv = *((const ushort4*)(buf + (size_t)(base + r) * NF + c4 * 4));
            float4 av = ((const float4*)ab)[c4];
            float4 cv = ((const float4*)(ab + 128))[c4];
            u.x = f2bf(bf2f(hv.x) * av.x + cv.x);
            u.y = f2bf(bf2f(hv.y) * av.y + cv.y);
            u.z = f2bf(bf2f(hv.z) * av.z + cv.z);
            u.w = f2bf(bf2f(hv.w) * av.w + cv.w);
        }
        *((ushort4*)&At[r][c4 * 4]) = u;
    }
    __syncthreads();

    int wave = t >> 6, lane = t & 63;
    int m0 = (wave & 1) * 16;
    int n0 = (wave >> 1) * 64;
    int l15 = lane & 15, q = lane >> 4;

    f32x4 acc[4];
#pragma unroll
    for (int i = 0; i < 4; i++) acc[i] = (f32x4){0.f, 0.f, 0.f, 0.f};

#pragma unroll
    for (int kc = 0; kc < 4; kc++) {
        short8 a = *((const short8*)&At[m0 + l15][kc * 32 + q * 8]);
#pragma unroll
        for (int tile = 0; tile < 4; tile++) {
            short8 b = *((const short8*)(Wb + (size_t)(n0 + 16 * tile + l15) * 128 + kc * 32 + q * 8));
            acc[tile] = __builtin_amdgcn_mfma_f32_16x16x32_bf16(a, b, acc[tile], 0, 0, 0);
        }
    }

#pragma unroll
    for (int tile = 0; tile < 4; tile++) {
        int col = n0 + 16 * tile + l15;
        float bias = b2[col];
#pragma unroll
        for (int reg = 0; reg < 4; reg++) {
            int row = q * 4 + reg;
            Ht[m0 + row][col] = acc[tile][reg] + bias;
        }
    }
    __syncthreads();

    for (int i = t; i < G_ROWS * 32; i += 256) {
        int r = i >> 5, c4 = i & 31;
        int row = base + r;
        if (row < N_NODES)
            *((float4*)(out + (size_t)row * NF + c4 * 4)) = *((const float4*)&Ht[r][c4 * 4]);
    }
}

// =============== fp32 fallback path (ws too small) ===========================
__global__ void finalize_bn(const float* __restrict__ stats,
                            const float* __restrict__ gamma,
                            const float* __restrict__ beta,
                            float* __restrict__ ab) {
    int f = threadIdx.x;
    if (f < 128) {
        float mean = stats[f] * (1.0f / N_NODES);
        float var = stats[128 + f] * (1.0f / N_NODES) - mean * mean;
        float rstd = rsqrtf(var + BN_EPS);
        float a = gamma[f] * rstd;
        float c = beta[f] - mean * a;
        ab[f] = a;
        ab[128 + f] = c;
    }
}

__global__ __launch_bounds__(256) void fused_gather_gemm1_f32(
    const float* __restrict__ xv,
    const int* __restrict__ rowptr,
    const int* __restrict__ ssrc,
    const unsigned short* __restrict__ Wb,
    const float* __restrict__ b1,
    float* __restrict__ hout,
    float* __restrict__ stats) {
    __shared__ unsigned short At[G_ROWS][AP];
    __shared__ float Ht[G_ROWS][HP];

    int t = threadIdx.x;
    int wave = t >> 6, lane = t & 63;
    int base = blockIdx.x * G_ROWS;
    int nrows = N_NODES - base; if (nrows > G_ROWS) nrows = G_ROWS;

    const float2* xf2 = (const float2*)xv;

    for (int nn = 0; nn < 8; nn++) {
        int r = wave * 8 + nn;
        int node = base + r;
        float2 acc = make_float2(0.f, 0.f);
        if (node < N_NODES) {
            acc = xf2[(size_t)node * 64 + lane];
            int beg = rowptr[node], end = rowptr[node + 1];
            for (int e = beg; e < end; e++) {
                float2 v0 = xf2[(size_t)ssrc[e] * 64 + lane];
                acc.x += v0.x;
                acc.y += v0.y;
            }
        }
        unsigned int packed = ((unsigned int)f2bf(acc.y) << 16) | (unsigned int)f2bf(acc.x);
        *((unsigned int*)&At[r][lane * 2]) = packed;
    }
    __syncthreads();

    int m0 = (wave & 1) * 16;
    int n0 = (wave >> 1) * 64;
    int l15 = lane & 15, q = lane >> 4;

    f32x4 acc[4];
#pragma unroll
    for (int i = 0; i < 4; i++) acc[i] = (f32x4){0.f, 0.f, 0.f, 0.f};

#pragma unroll
    for (int kc = 0; kc < 4; kc++) {
        short8 a = *((const short8*)&At[m0 + l15][kc * 32 + q * 8]);
#pragma unroll
        for (int tile = 0; tile < 4; tile++) {
            short8 b = *((const short8*)(Wb + (size_t)(n0 + 16 * tile + l15) * 128 + kc * 32 + q * 8));
            acc[tile] = __builtin_amdgcn_mfma_f32_16x16x32_bf16(a, b, acc[tile], 0, 0, 0);
        }
    }

#pragma unroll
    for (int tile = 0; tile < 4; tile++) {
        int col = n0 + 16 * tile + l15;
        float bias = b1[col];
#pragma unroll
        for (int reg = 0; reg < 4; reg++) {
            int row = q * 4 + reg;
            Ht[m0 + row][col] = fmaxf(acc[tile][reg] + bias, 0.f);
        }
    }
    __syncthreads();

    for (int i = t; i < G_ROWS * 32; i += 256) {
        int r = i >> 5, c4 = i & 31;
        int row = base + r;
        if (row < N_NODES)
            *((float4*)(hout + (size_t)row * NF + c4 * 4)) = *((const float4*)&Ht[r][c4 * 4]);
    }

    if (t < 128) {
        float s = 0.f, sq = 0.f;
        for (int r = 0; r < nrows; r++) {
            float v = Ht[r][t];
            s += v; sq += v * v;
        }
        atomicAdd(&stats[t], s);
        atomicAdd(&stats[128 + t], sq);
    }
}

__global__ __launch_bounds__(256) void gemm2_f32(
    float* __restrict__ h,
    const unsigned short* __restrict__ Wb,
    const float* __restrict__ b2,
    const float* __restrict__ ab) {
    __shared__ unsigned short At[G_ROWS][AP];
    __shared__ float Ht[G_ROWS][HP];

    int t = threadIdx.x;
    int base = blockIdx.x * G_ROWS;
    int nrows = N_NODES - base; if (nrows > G_ROWS) nrows = G_ROWS;

    for (int i = t; i < G_ROWS * 32; i += 256) {
        int r = i >> 5, c4 = i & 31;
        float4 v = make_float4(0.f, 0.f, 0.f, 0.f);
        if (r < nrows) {
            float4 hv = ((const float4*)(h + (size_t)(base + r) * NF))[c4];
            float4 av = ((const float4*)ab)[c4];
            float4 cv = ((const float4*)(ab + 128))[c4];
            v.x = hv.x * av.x + cv.x;
            v.y = hv.y * av.y + cv.y;
            v.z = hv.z * av.z + cv.z;
            v.w = hv.w * av.w + cv.w;
        }
        ushort4 u;
        u.x = f2bf(v.x); u.y = f2bf(v.y); u.z = f2bf(v.z); u.w = f2bf(v.w);
        *((ushort4*)&At[r][c4 * 4]) = u;
    }
    __syncthreads();

    int wave = t >> 6, lane = t & 63;
    int m0 = (wave & 1) * 16;
    int n0 = (wave >> 1) * 64;
    int l15 = lane & 15, q = lane >> 4;

    f32x4 acc[4];
#pragma unroll
    for (int i = 0; i < 4; i++) acc[i] = (f32x4){0.f, 0.f, 0.f, 0.f};

#pragma unroll
    for (int kc = 0; kc < 4; kc++) {
        short8 a = *((const short8*)&At[m0 + l15][kc * 32 + q * 8]);
#pragma unroll
        for (int tile = 0; tile < 4; tile++) {
            short8 b = *((const short8*)(Wb + (size_t)(n0 + 16 * tile + l15) * 128 + kc * 32 + q * 8));
            acc[tile] = __builtin_amdgcn_mfma_f32_16x16x32_bf16(a, b, acc[tile], 0, 0, 0);
        }
    }

#pragma unroll
    for (int tile = 0; tile < 4; tile++) {
        int col = n0 + 16 * tile + l15;
        float bias = b2[col];
#pragma unroll
        for (int reg = 0; reg < 4; reg++) {
            int row = q * 4 + reg;
            Ht[m0 + row][col] = acc[tile][reg] + bias;
        }
    }
    __syncthreads();

    for (int i = t; i < G_ROWS * 32; i += 256) {
        int r = i >> 5, c4 = i & 31;
        int row = base + r;
        if (row < N_NODES)
            *((float4*)(h + (size_t)row * NF + c4 * 4)) = *((const float4*)&Ht[r][c4 * 4]);
    }
}

extern "C" void kernel_launch(void* const* d_in, const int* in_sizes, int n_in,
                              void* d_out, int out_size, void* d_ws, size_t ws_size,
                              hipStream_t stream) {
    const float* x     = (const float*)d_in[0];
    const int*   ei    = (const int*)d_in[1];
    const float* W1    = (const float*)d_in[2];
    const float* b1    = (const float*)d_in[3];
    const float* gamma = (const float*)d_in[4];
    const float* beta  = (const float*)d_in[5];
    const float* W2    = (const float*)d_in[6];
    const float* b2    = (const float*)d_in[7];

    float* out = (float*)d_out;

    // Workspace layout
    float*          stats    = (float*)d_ws;                // 256 f (fallback)
    float*          ab       = stats + 256;                 // 256 f
    float*          P        = ab + 256;                    // 256*NB f (~1.6 MB)
    unsigned short* Wb1      = (unsigned short*)(P + 256 * NB); // 16384 us
    unsigned short* Wb2      = Wb1 + 128 * 128;             // 16384 us
    int*            counts   = (int*)(Wb2 + 128 * 128);     // 50000 i
    int*            rowptr   = counts + N_NODES;            // 50001 i
    int*            partials = rowptr + N_NODES + 1;        // 256 i (+pad)
    int*            rank     = partials + 256;              // 800000 i
    int*            ssrc     = rank + N_EDGES;              // 800000 i
    unsigned short* xb       = (unsigned short*)(ssrc + N_EDGES);   // 6.4M us
    unsigned short* buf      = xb + (size_t)N_NODES * NF;           // 6.4M us

    size_t need = (size_t)((char*)(buf + (size_t)N_NODES * NF) - (char*)d_ws);
    bool bf16_path = ws_size >= need;

    int dev = 0, coop_ok = 0;
    hipGetDevice(&dev);
    hipDeviceGetAttribute(&coop_ok, hipDeviceAttributeCooperativeLaunch, dev);

    if (bf16_path) {
        if (coop_ok) {
            void* args[12] = {(void*)&x, (void*)&xb, (void*)&W1, (void*)&W2,
                              (void*)&Wb1, (void*)&Wb2, (void*)&ei, (void*)&counts,
                              (void*)&rank, (void*)&partials, (void*)&rowptr, (void*)&ssrc};
            hipLaunchCooperativeKernel((void*)build_coop, dim3(COOP_BLOCKS), dim3(256),
                                       args, 0, stream);
        } else {
            int total = SETUP_C + SETUP_P + N_NODES + 256;
            setup_kernel<<<(total + 255) / 256, 256, 0, stream>>>(
                x, xb, W1, W2, Wb1, Wb2, counts, stats, 1);
            hist_kernel<<<(N_EDGES + 255) / 256, 256, 0, stream>>>(ei, counts, rank);
            scan_reduce<<<SCAN_BLOCKS, 256, 0, stream>>>(counts, partials);
            scan_partials2<<<1, 256, 0, stream>>>(partials);
            scan_apply<<<SCAN_BLOCKS, 256, 0, stream>>>(counts, partials, rowptr);
            fill_kernel<<<(N_EDGES + 255) / 256, 256, 0, stream>>>(ei, rowptr, rank, ssrc);
        }
        gather_bf16<<<(N_NODES * 64) / 256, 256, 0, stream>>>(xb, rowptr, ssrc, buf);
        gemm1_bf16<<<GBLOCKS, 256, 0, stream>>>(buf, Wb1, b1, P);
        bn_reduce<<<128, 256, 0, stream>>>(P, gamma, beta, ab);
        gemm2_bf16<<<GBLOCKS, 256, 0, stream>>>(buf, Wb2, b2, ab, out);
    } else {
        int total = SETUP_P + N_NODES + 256;
        setup_kernel<<<(total + 255) / 256, 256, 0, stream>>>(
            x, xb, W1, W2, Wb1, Wb2, counts, stats, 0);
        hist_kernel<<<(N_EDGES + 255) / 256, 256, 0, stream>>>(ei, counts, rank);
        scan_reduce<<<SCAN_BLOCKS, 256, 0, stream>>>(counts, partials);
        scan_partials2<<<1, 256, 0, stream>>>(partials);
        scan_apply<<<SCAN_BLOCKS, 256, 0, stream>>>(counts, partials, rowptr);
        fill_kernel<<<(N_EDGES + 255) / 256, 256, 0, stream>>>(ei, rowptr, rank, ssrc);
        fused_gather_gemm1_f32<<<GBLOCKS, 256, 0, stream>>>(
            x, rowptr, ssrc, Wb1, b1, out, stats);
        finalize_bn<<<1, 128, 0, stream>>>(stats, gamma, beta, ab);
        gemm2_f32<<<GBLOCKS, 256, 0, stream>>>(out, Wb2, b2, ab);
    }
}

// Round 11
// 241.362 us; speedup vs baseline: 3.1291x; 3.1291x over previous
//
#include <hip/hip_runtime.h>

#define N_NODES 50000
#define N_EDGES 800000
#define NF 128
#define BN_EPS 1e-5f
#define G_ROWS 32
#define GBLOCKS ((N_NODES + G_ROWS - 1) / G_ROWS)   // 1563
#define NB 1568   // padded partials pitch (>= GBLOCKS, mult of 32)
#define SCAN_BLOCKS ((N_NODES + 255) / 256)  // 196
#define AP 136  // bf16 A-tile pitch (shorts); 272B rows, 16B aligned
#define HP 132  // fp32 H-tile pitch

typedef __attribute__((ext_vector_type(8))) short short8;
typedef __attribute__((ext_vector_type(4))) float f32x4;

__device__ __forceinline__ unsigned short f2bf(float f) {
    union { float f; unsigned int i; } v; v.f = f;
    unsigned int r = (v.i + 0x7fffu + ((v.i >> 16) & 1u)) >> 16;
    return (unsigned short)r;
}
__device__ __forceinline__ float bf2f(unsigned short u) {
    union { unsigned int i; float f; } v; v.i = ((unsigned int)u) << 16; return v.f;
}
__device__ __forceinline__ float bflo(unsigned int u) { return bf2f((unsigned short)(u & 0xffffu)); }
__device__ __forceinline__ float bfhi(unsigned int u) { return bf2f((unsigned short)(u >> 16)); }

// ---------------- Setup: convert x->bf16 (opt), weights->bf16, zero bufs ------
#define SETUP_C (N_NODES * NF / 4)
#define SETUP_P (128 * 128)
__global__ void setup_kernel(const float* __restrict__ x, unsigned short* __restrict__ xb,
                             const float* __restrict__ W1, const float* __restrict__ W2,
                             unsigned short* __restrict__ Wb1, unsigned short* __restrict__ Wb2,
                             int* __restrict__ counts, float* __restrict__ stats,
                             int do_convert) {
    int i = blockIdx.x * blockDim.x + threadIdx.x;
    int off = do_convert ? 0 : SETUP_C;
    i += off;
    if (i < SETUP_C) {
        float4 v = ((const float4*)x)[i];
        ushort4 u;
        u.x = f2bf(v.x); u.y = f2bf(v.y); u.z = f2bf(v.z); u.w = f2bf(v.w);
        ((ushort4*)xb)[i] = u;
    } else if (i < SETUP_C + SETUP_P) {
        int j = i - SETUP_C;
        Wb1[j] = f2bf(W1[j]);
        Wb2[j] = f2bf(W2[j]);
    } else if (i < SETUP_C + SETUP_P + N_NODES) {
        counts[i - SETUP_C - SETUP_P] = 0;
    } else if (i < SETUP_C + SETUP_P + N_NODES + 256) {
        stats[i - SETUP_C - SETUP_P - N_NODES] = 0.0f;
    }
}

// ---------------- CSR build (counting sort by dst, rank-trick) ----------------
__global__ void hist_kernel(const int* __restrict__ ei, int* __restrict__ counts,
                            int* __restrict__ rank) {
    int t = blockIdx.x * blockDim.x + threadIdx.x;
    if (t < N_EDGES) rank[t] = atomicAdd(&counts[ei[N_EDGES + t]], 1);
}

__global__ __launch_bounds__(256) void scan_reduce(const int* __restrict__ counts,
                                                   int* __restrict__ partials) {
    __shared__ int red[256];
    int t = threadIdx.x;
    int i = blockIdx.x * 256 + t;
    red[t] = (i < N_NODES) ? counts[i] : 0;
    __syncthreads();
    for (int off = 128; off > 0; off >>= 1) {
        if (t < off) red[t] += red[t + off];
        __syncthreads();
    }
    if (t == 0) partials[blockIdx.x] = red[0];
}

__global__ __launch_bounds__(256) void scan_partials2(int* __restrict__ partials) {
    __shared__ int s[256];
    int t = threadIdx.x;
    int v = (t < SCAN_BLOCKS) ? partials[t] : 0;
    s[t] = v;
    __syncthreads();
    for (int off = 1; off < 256; off <<= 1) {
        int u = (t >= off) ? s[t - off] : 0;
        __syncthreads();
        s[t] += u;
        __syncthreads();
    }
    if (t < SCAN_BLOCKS) partials[t] = s[t] - v;
}

__global__ __launch_bounds__(256) void scan_apply(const int* __restrict__ counts,
                                                  const int* __restrict__ partials,
                                                  int* __restrict__ rowptr) {
    __shared__ int s[256];
    int t = threadIdx.x;
    int i = blockIdx.x * 256 + t;
    int v = (i < N_NODES) ? counts[i] : 0;
    s[t] = v;
    __syncthreads();
    for (int off = 1; off < 256; off <<= 1) {
        int u = (t >= off) ? s[t - off] : 0;
        __syncthreads();
        s[t] += u;
        __syncthreads();
    }
    int excl = partials[blockIdx.x] + s[t] - v;
    if (i < N_NODES) rowptr[i] = excl;
    if (i == 0) rowptr[N_NODES] = N_EDGES;
}

__global__ void fill_kernel(const int* __restrict__ ei,
                            const int* __restrict__ rowptr,
                            const int* __restrict__ rank,
                            int* __restrict__ ssrc) {
    int t = blockIdx.x * blockDim.x + threadIdx.x;
    if (t < N_EDGES) {
        int dst = ei[N_EDGES + t];
        ssrc[rowptr[dst] + rank[t]] = ei[t];
    }
}

// -------- Gather (bf16, pairwise): one wave per node, 2 neighbors/load-inst --
__global__ __launch_bounds__(256) void gather_bf16(const unsigned short* __restrict__ xb,
                                                   const int* __restrict__ rowptr,
                                                   const int* __restrict__ ssrc,
                                                   unsigned short* __restrict__ buf) {
    int node = (blockIdx.x * blockDim.x + threadIdx.x) >> 6;
    int lane = threadIdx.x & 63;
    if (node >= N_NODES) return;
    int half = lane >> 5;
    int fl = lane & 31;
    const uint2* x4 = (const uint2*)xb;  // 8 B = 4 bf16 features

    float a0 = 0.f, a1 = 0.f, a2 = 0.f, a3 = 0.f;
    if (half == 0) {
        uint2 u = x4[(size_t)node * 32 + fl];
        a0 = bflo(u.x); a1 = bfhi(u.x); a2 = bflo(u.y); a3 = bfhi(u.y);
    }
    int beg = rowptr[node], end = rowptr[node + 1];
    int e = beg;
    for (; e + 3 < end; e += 4) {  // 4 neighbors per iter, 2 loads/lane
        int sA = ssrc[e + half];
        int sB = ssrc[e + 2 + half];
        uint2 uA = x4[(size_t)sA * 32 + fl];
        uint2 uB = x4[(size_t)sB * 32 + fl];
        a0 += bflo(uA.x) + bflo(uB.x);
        a1 += bfhi(uA.x) + bfhi(uB.x);
        a2 += bflo(uA.y) + bflo(uB.y);
        a3 += bfhi(uA.y) + bfhi(uB.y);
    }
    for (; e + 1 < end; e += 2) {  // 2 neighbors, 1 load/lane
        int s = ssrc[e + half];
        uint2 u = x4[(size_t)s * 32 + fl];
        a0 += bflo(u.x); a1 += bfhi(u.x);
        a2 += bflo(u.y); a3 += bfhi(u.y);
    }
    if (e < end && half == 0) {    // odd tail: lower half only
        int s = ssrc[e];
        uint2 u = x4[(size_t)s * 32 + fl];
        a0 += bflo(u.x); a1 += bfhi(u.x);
        a2 += bflo(u.y); a3 += bfhi(u.y);
    }
    a0 += __shfl_xor(a0, 32);
    a1 += __shfl_xor(a1, 32);
    a2 += __shfl_xor(a2, 32);
    a3 += __shfl_xor(a3, 32);
    if (half == 0) {
        uint2 o;
        o.x = ((unsigned int)f2bf(a1) << 16) | (unsigned int)f2bf(a0);
        o.y = ((unsigned int)f2bf(a3) << 16) | (unsigned int)f2bf(a2);
        ((uint2*)buf)[(size_t)node * 32 + fl] = o;
    }
}

// ------- GEMM1 (bf16 in-place): buf = bf16(relu(buf @ W1^T + b1)) ------------
__global__ __launch_bounds__(256) void gemm1_bf16(
    unsigned short* __restrict__ buf,
    const unsigned short* __restrict__ Wb,
    const float* __restrict__ b1,
    float* __restrict__ P) {
    __shared__ unsigned short At[G_ROWS][AP];
    __shared__ float Ht[G_ROWS][HP];

    int t = threadIdx.x;
    int base = blockIdx.x * G_ROWS;
    int nrows = N_NODES - base; if (nrows > G_ROWS) nrows = G_ROWS;

    for (int i = t; i < G_ROWS * 16; i += 256) {
        int r = i >> 4, c8 = i & 15;
        uint4 v = make_uint4(0u, 0u, 0u, 0u);
        if (r < nrows) v = ((const uint4*)(buf + (size_t)(base + r) * NF))[c8];
        *((uint4*)&At[r][c8 * 8]) = v;
    }
    __syncthreads();

    int wave = t >> 6, lane = t & 63;
    int m0 = (wave & 1) * 16;
    int n0 = (wave >> 1) * 64;
    int l15 = lane & 15, q = lane >> 4;

    f32x4 acc[4];
#pragma unroll
    for (int i = 0; i < 4; i++) acc[i] = (f32x4){0.f, 0.f, 0.f, 0.f};

#pragma unroll
    for (int kc = 0; kc < 4; kc++) {
        short8 a = *((const short8*)&At[m0 + l15][kc * 32 + q * 8]);
#pragma unroll
        for (int tile = 0; tile < 4; tile++) {
            short8 b = *((const short8*)(Wb + (size_t)(n0 + 16 * tile + l15) * 128 + kc * 32 + q * 8));
            acc[tile] = __builtin_amdgcn_mfma_f32_16x16x32_bf16(a, b, acc[tile], 0, 0, 0);
        }
    }

#pragma unroll
    for (int tile = 0; tile < 4; tile++) {
        int col = n0 + 16 * tile + l15;
        float bias = b1[col];
#pragma unroll
        for (int reg = 0; reg < 4; reg++) {
            int row = q * 4 + reg;
            Ht[m0 + row][col] = fmaxf(acc[tile][reg] + bias, 0.f);
        }
    }
    __syncthreads();

    for (int i = t; i < G_ROWS * 32; i += 256) {
        int r = i >> 5, c4 = i & 31;
        int row = base + r;
        if (row < N_NODES) {
            float4 v = *((const float4*)&Ht[r][c4 * 4]);
            ushort4 u;
            u.x = f2bf(v.x); u.y = f2bf(v.y); u.z = f2bf(v.z); u.w = f2bf(v.w);
            *((ushort4*)(buf + (size_t)row * NF + c4 * 4)) = u;
        }
    }

    {
        int f = t & 127;
        bool issq = (t >= 128);
        float s = 0.f;
        for (int r = 0; r < nrows; r++) {
            float v = Ht[r][f];
            s += issq ? v * v : v;
        }
        P[(size_t)t * NB + blockIdx.x] = s;
    }
}

// ------- BN reduce + fold (no atomics) ---------------------------------------
__global__ __launch_bounds__(256) void bn_reduce(const float* __restrict__ P,
                                                 const float* __restrict__ gamma,
                                                 const float* __restrict__ beta,
                                                 float* __restrict__ ab) {
    __shared__ float s1[256], s2[256];
    int f = blockIdx.x;
    int j = threadIdx.x;
    float a = 0.f, b = 0.f;
    for (int k = j; k < GBLOCKS; k += 256) {
        a += P[(size_t)f * NB + k];
        b += P[(size_t)(128 + f) * NB + k];
    }
    s1[j] = a; s2[j] = b;
    __syncthreads();
    for (int off = 128; off > 0; off >>= 1) {
        if (j < off) { s1[j] += s1[j + off]; s2[j] += s2[j + off]; }
        __syncthreads();
    }
    if (j == 0) {
        float mean = s1[0] * (1.0f / N_NODES);
        float var = s2[0] * (1.0f / N_NODES) - mean * mean;
        float rstd = rsqrtf(var + BN_EPS);
        float aa = gamma[f] * rstd;
        float cc = beta[f] - mean * aa;
        ab[f] = aa;
        ab[128 + f] = cc;
    }
}

// -------- GEMM2 (bf16 in, fp32 out) ------------------------------------------
__global__ __launch_bounds__(256) void gemm2_bf16(
    const unsigned short* __restrict__ buf,
    const unsigned short* __restrict__ Wb,
    const float* __restrict__ b2,
    const float* __restrict__ ab,
    float* __restrict__ out) {
    __shared__ unsigned short At[G_ROWS][AP];
    __shared__ float Ht[G_ROWS][HP];

    int t = threadIdx.x;
    int base = blockIdx.x * G_ROWS;
    int nrows = N_NODES - base; if (nrows > G_ROWS) nrows = G_ROWS;

    for (int i = t; i < G_ROWS * 32; i += 256) {
        int r = i >> 5, c4 = i & 31;
        ushort4 u = make_ushort4(0, 0, 0, 0);
        if (r < nrows) {
            ushort4 hv = *((const ushort4*)(buf + (size_t)(base + r) * NF + c4 * 4));
            float4 av = ((const float4*)ab)[c4];
            float4 cv = ((const float4*)(ab + 128))[c4];
            u.x = f2bf(bf2f(hv.x) * av.x + cv.x);
            u.y = f2bf(bf2f(hv.y) * av.y + cv.y);
            u.z = f2bf(bf2f(hv.z) * av.z + cv.z);
            u.w = f2bf(bf2f(hv.w) * av.w + cv.w);
        }
        *((ushort4*)&At[r][c4 * 4]) = u;
    }
    __syncthreads();

    int wave = t >> 6, lane = t & 63;
    int m0 = (wave & 1) * 16;
    int n0 = (wave >> 1) * 64;
    int l15 = lane & 15, q = lane >> 4;

    f32x4 acc[4];
#pragma unroll
    for (int i = 0; i < 4; i++) acc[i] = (f32x4){0.f, 0.f, 0.f, 0.f};

#pragma unroll
    for (int kc = 0; kc < 4; kc++) {
        short8 a = *((const short8*)&At[m0 + l15][kc * 32 + q * 8]);
#pragma unroll
        for (int tile = 0; tile < 4; tile++) {
            short8 b = *((const short8*)(Wb + (size_t)(n0 + 16 * tile + l15) * 128 + kc * 32 + q * 8));
            acc[tile] = __builtin_amdgcn_mfma_f32_16x16x32_bf16(a, b, acc[tile], 0, 0, 0);
        }
    }

#pragma unroll
    for (int tile = 0; tile < 4; tile++) {
        int col = n0 + 16 * tile + l15;
        float bias = b2[col];
#pragma unroll
        for (int reg = 0; reg < 4; reg++) {
            int row = q * 4 + reg;
            Ht[m0 + row][col] = acc[tile][reg] + bias;
        }
    }
    __syncthreads();

    for (int i = t; i < G_ROWS * 32; i += 256) {
        int r = i >> 5, c4 = i & 31;
        int row = base + r;
        if (row < N_NODES)
            *((float4*)(out + (size_t)row * NF + c4 * 4)) = *((const float4*)&Ht[r][c4 * 4]);
    }
}

// =============== fp32 fallback path (ws too small) ===========================
__global__ void finalize_bn(const float* __restrict__ stats,
                            const float* __restrict__ gamma,
                            const float* __restrict__ beta,
                            float* __restrict__ ab) {
    int f = threadIdx.x;
    if (f < 128) {
        float mean = stats[f] * (1.0f / N_NODES);
        float var = stats[128 + f] * (1.0f / N_NODES) - mean * mean;
        float rstd = rsqrtf(var + BN_EPS);
        float a = gamma[f] * rstd;
        float c = beta[f] - mean * a;
        ab[f] = a;
        ab[128 + f] = c;
    }
}

__global__ __launch_bounds__(256) void fused_gather_gemm1_f32(
    const float* __restrict__ xv,
    const int* __restrict__ rowptr,
    const int* __restrict__ ssrc,
    const unsigned short* __restrict__ Wb,
    const float* __restrict__ b1,
    float* __restrict__ hout,
    float* __restrict__ stats) {
    __shared__ unsigned short At[G_ROWS][AP];
    __shared__ float Ht[G_ROWS][HP];

    int t = threadIdx.x;
    int wave = t >> 6, lane = t & 63;
    int base = blockIdx.x * G_ROWS;
    int nrows = N_NODES - base; if (nrows > G_ROWS) nrows = G_ROWS;

    const float2* xf2 = (const float2*)xv;

    for (int nn = 0; nn < 8; nn++) {
        int r = wave * 8 + nn;
        int node = base + r;
        float2 acc = make_float2(0.f, 0.f);
        if (node < N_NODES) {
            acc = xf2[(size_t)node * 64 + lane];
            int beg = rowptr[node], end = rowptr[node + 1];
            for (int e = beg; e < end; e++) {
                float2 v0 = xf2[(size_t)ssrc[e] * 64 + lane];
                acc.x += v0.x;
                acc.y += v0.y;
            }
        }
        unsigned int packed = ((unsigned int)f2bf(acc.y) << 16) | (unsigned int)f2bf(acc.x);
        *((unsigned int*)&At[r][lane * 2]) = packed;
    }
    __syncthreads();

    int m0 = (wave & 1) * 16;
    int n0 = (wave >> 1) * 64;
    int l15 = lane & 15, q = lane >> 4;

    f32x4 acc[4];
#pragma unroll
    for (int i = 0; i < 4; i++) acc[i] = (f32x4){0.f, 0.f, 0.f, 0.f};

#pragma unroll
    for (int kc = 0; kc < 4; kc++) {
        short8 a = *((const short8*)&At[m0 + l15][kc * 32 + q * 8]);
#pragma unroll
        for (int tile = 0; tile < 4; tile++) {
            short8 b = *((const short8*)(Wb + (size_t)(n0 + 16 * tile + l15) * 128 + kc * 32 + q * 8));
            acc[tile] = __builtin_amdgcn_mfma_f32_16x16x32_bf16(a, b, acc[tile], 0, 0, 0);
        }
    }

#pragma unroll
    for (int tile = 0; tile < 4; tile++) {
        int col = n0 + 16 * tile + l15;
        float bias = b1[col];
#pragma unroll
        for (int reg = 0; reg < 4; reg++) {
            int row = q * 4 + reg;
            Ht[m0 + row][col] = fmaxf(acc[tile][reg] + bias, 0.f);
        }
    }
    __syncthreads();

    for (int i = t; i < G_ROWS * 32; i += 256) {
        int r = i >> 5, c4 = i & 31;
        int row = base + r;
        if (row < N_NODES)
            *((float4*)(hout + (size_t)row * NF + c4 * 4)) = *((const float4*)&Ht[r][c4 * 4]);
    }

    if (t < 128) {
        float s = 0.f, sq = 0.f;
        for (int r = 0; r < nrows; r++) {
            float v = Ht[r][t];
            s += v; sq += v * v;
        }
        atomicAdd(&stats[t], s);
        atomicAdd(&stats[128 + t], sq);
    }
}

__global__ __launch_bounds__(256) void gemm2_f32(
    float* __restrict__ h,
    const unsigned short* __restrict__ Wb,
    const float* __restrict__ b2,
    const float* __restrict__ ab) {
    __shared__ unsigned short At[G_ROWS][AP];
    __shared__ float Ht[G_ROWS][HP];

    int t = threadIdx.x;
    int base = blockIdx.x * G_ROWS;
    int nrows = N_NODES - base; if (nrows > G_ROWS) nrows = G_ROWS;

    for (int i = t; i < G_ROWS * 32; i += 256) {
        int r = i >> 5, c4 = i & 31;
        float4 v = make_float4(0.f, 0.f, 0.f, 0.f);
        if (r < nrows) {
            float4 hv = ((const float4*)(h + (size_t)(base + r) * NF))[c4];
            float4 av = ((const float4*)ab)[c4];
            float4 cv = ((const float4*)(ab + 128))[c4];
            v.x = hv.x * av.x + cv.x;
            v.y = hv.y * av.y + cv.y;
            v.z = hv.z * av.z + cv.z;
            v.w = hv.w * av.w + cv.w;
        }
        ushort4 u;
        u.x = f2bf(v.x); u.y = f2bf(v.y); u.z = f2bf(v.z); u.w = f2bf(v.w);
        *((ushort4*)&At[r][c4 * 4]) = u;
    }
    __syncthreads();

    int wave = t >> 6, lane = t & 63;
    int m0 = (wave & 1) * 16;
    int n0 = (wave >> 1) * 64;
    int l15 = lane & 15, q = lane >> 4;

    f32x4 acc[4];
#pragma unroll
    for (int i = 0; i < 4; i++) acc[i] = (f32x4){0.f, 0.f, 0.f, 0.f};

#pragma unroll
    for (int kc = 0; kc < 4; kc++) {
        short8 a = *((const short8*)&At[m0 + l15][kc * 32 + q * 8]);
#pragma unroll
        for (int tile = 0; tile < 4; tile++) {
            short8 b = *((const short8*)(Wb + (size_t)(n0 + 16 * tile + l15) * 128 + kc * 32 + q * 8));
            acc[tile] = __builtin_amdgcn_mfma_f32_16x16x32_bf16(a, b, acc[tile], 0, 0, 0);
        }
    }

#pragma unroll
    for (int tile = 0; tile < 4; tile++) {
        int col = n0 + 16 * tile + l15;
        float bias = b2[col];
#pragma unroll
        for (int reg = 0; reg < 4; reg++) {
            int row = q * 4 + reg;
            Ht[m0 + row][col] = acc[tile][reg] + bias;
        }
    }
    __syncthreads();

    for (int i = t; i < G_ROWS * 32; i += 256) {
        int r = i >> 5, c4 = i & 31;
        int row = base + r;
        if (row < N_NODES)
            *((float4*)(h + (size_t)row * NF + c4 * 4)) = *((const float4*)&Ht[r][c4 * 4]);
    }
}

extern "C" void kernel_launch(void* const* d_in, const int* in_sizes, int n_in,
                              void* d_out, int out_size, void* d_ws, size_t ws_size,
                              hipStream_t stream) {
    const float* x     = (const float*)d_in[0];
    const int*   ei    = (const int*)d_in[1];
    const float* W1    = (const float*)d_in[2];
    const float* b1    = (const float*)d_in[3];
    const float* gamma = (const float*)d_in[4];
    const float* beta  = (const float*)d_in[5];
    const float* W2    = (const float*)d_in[6];
    const float* b2    = (const float*)d_in[7];

    float* out = (float*)d_out;

    // Workspace layout
    float*          stats    = (float*)d_ws;                // 256 f (fallback)
    float*          ab       = stats + 256;                 // 256 f
    float*          P        = ab + 256;                    // 256*NB f (~1.6 MB)
    unsigned short* Wb1      = (unsigned short*)(P + 256 * NB); // 16384 us
    unsigned short* Wb2      = Wb1 + 128 * 128;             // 16384 us
    int*            counts   = (int*)(Wb2 + 128 * 128);     // 50000 i
    int*            rowptr   = counts + N_NODES;            // 50001 i
    int*            partials = rowptr + N_NODES + 1;        // 256 i (+pad)
    int*            rank     = partials + 256;              // 800000 i
    int*            ssrc     = rank + N_EDGES;              // 800000 i
    unsigned short* xb       = (unsigned short*)(ssrc + N_EDGES);   // 6.4M us
    unsigned short* buf      = xb + (size_t)N_NODES * NF;           // 6.4M us

    size_t need = (size_t)((char*)(buf + (size_t)N_NODES * NF) - (char*)d_ws);
    bool bf16_path = ws_size >= need;

    if (bf16_path) {
        int total = SETUP_C + SETUP_P + N_NODES + 256;
        setup_kernel<<<(total + 255) / 256, 256, 0, stream>>>(
            x, xb, W1, W2, Wb1, Wb2, counts, stats, 1);
    } else {
        int total = SETUP_P + N_NODES + 256;
        setup_kernel<<<(total + 255) / 256, 256, 0, stream>>>(
            x, xb, W1, W2, Wb1, Wb2, counts, stats, 0);
    }
    hist_kernel<<<(N_EDGES + 255) / 256, 256, 0, stream>>>(ei, counts, rank);
    scan_reduce<<<SCAN_BLOCKS, 256, 0, stream>>>(counts, partials);
    scan_partials2<<<1, 256, 0, stream>>>(partials);
    scan_apply<<<SCAN_BLOCKS, 256, 0, stream>>>(counts, partials, rowptr);
    fill_kernel<<<(N_EDGES + 255) / 256, 256, 0, stream>>>(ei, rowptr, rank, ssrc);

    if (bf16_path) {
        gather_bf16<<<(N_NODES * 64) / 256, 256, 0, stream>>>(xb, rowptr, ssrc, buf);
        gemm1_bf16<<<GBLOCKS, 256, 0, stream>>>(buf, Wb1, b1, P);
        bn_reduce<<<128, 256, 0, stream>>>(P, gamma, beta, ab);
        gemm2_bf16<<<GBLOCKS, 256, 0, stream>>>(buf, Wb2, b2, ab, out);
    } else {
        fused_gather_gemm1_f32<<<GBLOCKS, 256, 0, stream>>>(
            x, rowptr, ssrc, Wb1, b1, out, stats);
        finalize_bn<<<1, 128, 0, stream>>>(stats, gamma, beta, ab);
        gemm2_f32<<<GBLOCKS, 256, 0, stream>>>(out, Wb2, b2, ab);
    }
}

// Round 12
// 228.368 us; speedup vs baseline: 3.3071x; 1.0569x over previous
//
#include <hip/hip_runtime.h>

#define N_NODES 50000
#define N_EDGES 800000
#define NF 128
#define BN_EPS 1e-5f
#define G_ROWS 32
#define GBLOCKS ((N_NODES + G_ROWS - 1) / G_ROWS)   // 1563
#define NB 1568   // padded partials pitch
#define SCAN_BLOCKS ((N_NODES + 255) / 256)  // 196
#define AP 136  // bf16 A-tile pitch (shorts)
#define HP 132  // fp32 H-tile pitch

typedef __attribute__((ext_vector_type(8))) short short8;
typedef __attribute__((ext_vector_type(4))) float f32x4;

__device__ __forceinline__ unsigned short f2bf(float f) {
    union { float f; unsigned int i; } v; v.f = f;
    unsigned int r = (v.i + 0x7fffu + ((v.i >> 16) & 1u)) >> 16;
    return (unsigned short)r;
}
__device__ __forceinline__ float bf2f(unsigned short u) {
    union { unsigned int i; float f; } v; v.i = ((unsigned int)u) << 16; return v.f;
}
__device__ __forceinline__ float bflo(unsigned int u) { return bf2f((unsigned short)(u & 0xffffu)); }
__device__ __forceinline__ float bfhi(unsigned int u) { return bf2f((unsigned short)(u >> 16)); }

// ---------------- Setup ----------------
#define SETUP_C (N_NODES * NF / 4)
#define SETUP_P (128 * 128)
__global__ void setup_kernel(const float* __restrict__ x, unsigned short* __restrict__ xb,
                             const float* __restrict__ W1, const float* __restrict__ W2,
                             unsigned short* __restrict__ Wb1, unsigned short* __restrict__ Wb2,
                             int* __restrict__ counts, float* __restrict__ stats,
                             int do_convert) {
    int i = blockIdx.x * blockDim.x + threadIdx.x;
    int off = do_convert ? 0 : SETUP_C;
    i += off;
    if (i < SETUP_C) {
        float4 v = ((const float4*)x)[i];
        ushort4 u;
        u.x = f2bf(v.x); u.y = f2bf(v.y); u.z = f2bf(v.z); u.w = f2bf(v.w);
        ((ushort4*)xb)[i] = u;
    } else if (i < SETUP_C + SETUP_P) {
        int j = i - SETUP_C;
        Wb1[j] = f2bf(W1[j]);
        Wb2[j] = f2bf(W2[j]);
    } else if (i < SETUP_C + SETUP_P + N_NODES) {
        counts[i - SETUP_C - SETUP_P] = 0;
    } else if (i < SETUP_C + SETUP_P + N_NODES + 256) {
        stats[i - SETUP_C - SETUP_P - N_NODES] = 0.0f;
    }
}

// ---------------- CSR build (rank-trick) ----------------
__global__ void hist_kernel(const int* __restrict__ ei, int* __restrict__ counts,
                            int* __restrict__ rank) {
    int t = blockIdx.x * blockDim.x + threadIdx.x;
    if (t < N_EDGES) rank[t] = atomicAdd(&counts[ei[N_EDGES + t]], 1);
}

__global__ __launch_bounds__(256) void scan_reduce(const int* __restrict__ counts,
                                                   int* __restrict__ partials) {
    __shared__ int red[256];
    int t = threadIdx.x;
    int i = blockIdx.x * 256 + t;
    red[t] = (i < N_NODES) ? counts[i] : 0;
    __syncthreads();
    for (int off = 128; off > 0; off >>= 1) {
        if (t < off) red[t] += red[t + off];
        __syncthreads();
    }
    if (t == 0) partials[blockIdx.x] = red[0];
}

// scan_apply with fused partials-scan: each block redundantly scans the 196
// partials in LDS (trivial) -> its own exclusive offset; saves a dispatch.
__global__ __launch_bounds__(256) void scan_apply(const int* __restrict__ counts,
                                                  const int* __restrict__ partials,
                                                  int* __restrict__ rowptr) {
    __shared__ int sp[256];
    __shared__ int s[256];
    int t = threadIdx.x;

    int pv = (t < SCAN_BLOCKS) ? partials[t] : 0;
    sp[t] = pv;
    __syncthreads();
    for (int off = 1; off < 256; off <<= 1) {
        int u = (t >= off) ? sp[t - off] : 0;
        __syncthreads();
        sp[t] += u;
        __syncthreads();
    }
    int blockOff = (blockIdx.x == 0) ? 0 : sp[blockIdx.x - 1];

    int i = blockIdx.x * 256 + t;
    int v = (i < N_NODES) ? counts[i] : 0;
    s[t] = v;
    __syncthreads();
    for (int off = 1; off < 256; off <<= 1) {
        int u = (t >= off) ? s[t - off] : 0;
        __syncthreads();
        s[t] += u;
        __syncthreads();
    }
    int excl = blockOff + s[t] - v;
    if (i < N_NODES) rowptr[i] = excl;
    if (i == 0) rowptr[N_NODES] = N_EDGES;
}

__global__ void fill_kernel(const int* __restrict__ ei,
                            const int* __restrict__ rowptr,
                            const int* __restrict__ rank,
                            int* __restrict__ ssrc) {
    int t = blockIdx.x * blockDim.x + threadIdx.x;
    if (t < N_EDGES) {
        int dst = ei[N_EDGES + t];
        ssrc[rowptr[dst] + rank[t]] = ei[t];
    }
}

// -------- Gather (bf16): one wave per node, wave-uniform ssrc reads ----------
// Lane owns 2 features (one dword). ssrc[e] indices are wave-uniform ->
// compiler scalarizes them (s_load); 8 row loads in flight per iteration.
__global__ __launch_bounds__(256) void gather_bf16(const unsigned short* __restrict__ xb,
                                                   const int* __restrict__ rowptr,
                                                   const int* __restrict__ ssrc,
                                                   unsigned short* __restrict__ buf) {
    int node = (blockIdx.x * blockDim.x + threadIdx.x) >> 6;
    int lane = threadIdx.x & 63;
    if (node >= N_NODES) return;
    const unsigned int* x2 = (const unsigned int*)xb;
    unsigned int u = x2[(size_t)node * 64 + lane];
    float ax = bflo(u), ay = bfhi(u);
    int beg = rowptr[node], end = rowptr[node + 1];
    int e = beg;
    for (; e + 7 < end; e += 8) {
        unsigned int u0 = x2[(size_t)ssrc[e] * 64 + lane];
        unsigned int u1 = x2[(size_t)ssrc[e + 1] * 64 + lane];
        unsigned int u2 = x2[(size_t)ssrc[e + 2] * 64 + lane];
        unsigned int u3 = x2[(size_t)ssrc[e + 3] * 64 + lane];
        unsigned int u4 = x2[(size_t)ssrc[e + 4] * 64 + lane];
        unsigned int u5 = x2[(size_t)ssrc[e + 5] * 64 + lane];
        unsigned int u6 = x2[(size_t)ssrc[e + 6] * 64 + lane];
        unsigned int u7 = x2[(size_t)ssrc[e + 7] * 64 + lane];
        ax += bflo(u0) + bflo(u1) + bflo(u2) + bflo(u3)
            + bflo(u4) + bflo(u5) + bflo(u6) + bflo(u7);
        ay += bfhi(u0) + bfhi(u1) + bfhi(u2) + bfhi(u3)
            + bfhi(u4) + bfhi(u5) + bfhi(u6) + bfhi(u7);
    }
    for (; e + 3 < end; e += 4) {
        unsigned int u0 = x2[(size_t)ssrc[e] * 64 + lane];
        unsigned int u1 = x2[(size_t)ssrc[e + 1] * 64 + lane];
        unsigned int u2 = x2[(size_t)ssrc[e + 2] * 64 + lane];
        unsigned int u3 = x2[(size_t)ssrc[e + 3] * 64 + lane];
        ax += bflo(u0) + bflo(u1) + bflo(u2) + bflo(u3);
        ay += bfhi(u0) + bfhi(u1) + bfhi(u2) + bfhi(u3);
    }
    for (; e < end; e++) {
        unsigned int u0 = x2[(size_t)ssrc[e] * 64 + lane];
        ax += bflo(u0);
        ay += bfhi(u0);
    }
    unsigned int packed = ((unsigned int)f2bf(ay) << 16) | (unsigned int)f2bf(ax);
    ((unsigned int*)buf)[(size_t)node * 64 + lane] = packed;
}

// ------- GEMM1 (bf16 in-place): buf = bf16(relu(buf @ W1^T + b1)) ------------
__global__ __launch_bounds__(256) void gemm1_bf16(
    unsigned short* __restrict__ buf,
    const unsigned short* __restrict__ Wb,
    const float* __restrict__ b1,
    float* __restrict__ P) {
    __shared__ unsigned short At[G_ROWS][AP];
    __shared__ float Ht[G_ROWS][HP];

    int t = threadIdx.x;
    int base = blockIdx.x * G_ROWS;
    int nrows = N_NODES - base; if (nrows > G_ROWS) nrows = G_ROWS;

    for (int i = t; i < G_ROWS * 16; i += 256) {
        int r = i >> 4, c8 = i & 15;
        uint4 v = make_uint4(0u, 0u, 0u, 0u);
        if (r < nrows) v = ((const uint4*)(buf + (size_t)(base + r) * NF))[c8];
        *((uint4*)&At[r][c8 * 8]) = v;
    }
    __syncthreads();

    int wave = t >> 6, lane = t & 63;
    int m0 = (wave & 1) * 16;
    int n0 = (wave >> 1) * 64;
    int l15 = lane & 15, q = lane >> 4;

    f32x4 acc[4];
#pragma unroll
    for (int i = 0; i < 4; i++) acc[i] = (f32x4){0.f, 0.f, 0.f, 0.f};

#pragma unroll
    for (int kc = 0; kc < 4; kc++) {
        short8 a = *((const short8*)&At[m0 + l15][kc * 32 + q * 8]);
#pragma unroll
        for (int tile = 0; tile < 4; tile++) {
            short8 b = *((const short8*)(Wb + (size_t)(n0 + 16 * tile + l15) * 128 + kc * 32 + q * 8));
            acc[tile] = __builtin_amdgcn_mfma_f32_16x16x32_bf16(a, b, acc[tile], 0, 0, 0);
        }
    }

#pragma unroll
    for (int tile = 0; tile < 4; tile++) {
        int col = n0 + 16 * tile + l15;
        float bias = b1[col];
#pragma unroll
        for (int reg = 0; reg < 4; reg++) {
            int row = q * 4 + reg;
            Ht[m0 + row][col] = fmaxf(acc[tile][reg] + bias, 0.f);
        }
    }
    __syncthreads();

    for (int i = t; i < G_ROWS * 32; i += 256) {
        int r = i >> 5, c4 = i & 31;
        int row = base + r;
        if (row < N_NODES) {
            float4 v = *((const float4*)&Ht[r][c4 * 4]);
            ushort4 u;
            u.x = f2bf(v.x); u.y = f2bf(v.y); u.z = f2bf(v.z); u.w = f2bf(v.w);
            *((ushort4*)(buf + (size_t)row * NF + c4 * 4)) = u;
        }
    }

    {
        int f = t & 127;
        bool issq = (t >= 128);
        float s = 0.f;
        for (int r = 0; r < nrows; r++) {
            float v = Ht[r][f];
            s += issq ? v * v : v;
        }
        P[(size_t)t * NB + blockIdx.x] = s;
    }
}

// ------- BN reduce + fold (no atomics) ---------------------------------------
__global__ __launch_bounds__(256) void bn_reduce(const float* __restrict__ P,
                                                 const float* __restrict__ gamma,
                                                 const float* __restrict__ beta,
                                                 float* __restrict__ ab) {
    __shared__ float s1[256], s2[256];
    int f = blockIdx.x;
    int j = threadIdx.x;
    float a = 0.f, b = 0.f;
    for (int k = j; k < GBLOCKS; k += 256) {
        a += P[(size_t)f * NB + k];
        b += P[(size_t)(128 + f) * NB + k];
    }
    s1[j] = a; s2[j] = b;
    __syncthreads();
    for (int off = 128; off > 0; off >>= 1) {
        if (j < off) { s1[j] += s1[j + off]; s2[j] += s2[j + off]; }
        __syncthreads();
    }
    if (j == 0) {
        float mean = s1[0] * (1.0f / N_NODES);
        float var = s2[0] * (1.0f / N_NODES) - mean * mean;
        float rstd = rsqrtf(var + BN_EPS);
        float aa = gamma[f] * rstd;
        float cc = beta[f] - mean * aa;
        ab[f] = aa;
        ab[128 + f] = cc;
    }
}

// -------- GEMM2 (bf16 in, fp32 out) ------------------------------------------
__global__ __launch_bounds__(256) void gemm2_bf16(
    const unsigned short* __restrict__ buf,
    const unsigned short* __restrict__ Wb,
    const float* __restrict__ b2,
    const float* __restrict__ ab,
    float* __restrict__ out) {
    __shared__ unsigned short At[G_ROWS][AP];
    __shared__ float Ht[G_ROWS][HP];

    int t = threadIdx.x;
    int base = blockIdx.x * G_ROWS;
    int nrows = N_NODES - base; if (nrows > G_ROWS) nrows = G_ROWS;

    for (int i = t; i < G_ROWS * 32; i += 256) {
        int r = i >> 5, c4 = i & 31;
        ushort4 u = make_ushort4(0, 0, 0, 0);
        if (r < nrows) {
            ushort4 hv = *((const ushort4*)(buf + (size_t)(base + r) * NF + c4 * 4));
            float4 av = ((const float4*)ab)[c4];
            float4 cv = ((const float4*)(ab + 128))[c4];
            u.x = f2bf(bf2f(hv.x) * av.x + cv.x);
            u.y = f2bf(bf2f(hv.y) * av.y + cv.y);
            u.z = f2bf(bf2f(hv.z) * av.z + cv.z);
            u.w = f2bf(bf2f(hv.w) * av.w + cv.w);
        }
        *((ushort4*)&At[r][c4 * 4]) = u;
    }
    __syncthreads();

    int wave = t >> 6, lane = t & 63;
    int m0 = (wave & 1) * 16;
    int n0 = (wave >> 1) * 64;
    int l15 = lane & 15, q = lane >> 4;

    f32x4 acc[4];
#pragma unroll
    for (int i = 0; i < 4; i++) acc[i] = (f32x4){0.f, 0.f, 0.f, 0.f};

#pragma unroll
    for (int kc = 0; kc < 4; kc++) {
        short8 a = *((const short8*)&At[m0 + l15][kc * 32 + q * 8]);
#pragma unroll
        for (int tile = 0; tile < 4; tile++) {
            short8 b = *((const short8*)(Wb + (size_t)(n0 + 16 * tile + l15) * 128 + kc * 32 + q * 8));
            acc[tile] = __builtin_amdgcn_mfma_f32_16x16x32_bf16(a, b, acc[tile], 0, 0, 0);
        }
    }

#pragma unroll
    for (int tile = 0; tile < 4; tile++) {
        int col = n0 + 16 * tile + l15;
        float bias = b2[col];
#pragma unroll
        for (int reg = 0; reg < 4; reg++) {
            int row = q * 4 + reg;
            Ht[m0 + row][col] = acc[tile][reg] + bias;
        }
    }
    __syncthreads();

    for (int i = t; i < G_ROWS * 32; i += 256) {
        int r = i >> 5, c4 = i & 31;
        int row = base + r;
        if (row < N_NODES)
            *((float4*)(out + (size_t)row * NF + c4 * 4)) = *((const float4*)&Ht[r][c4 * 4]);
    }
}

// =============== fp32 fallback path (ws too small) ===========================
__global__ void finalize_bn(const float* __restrict__ stats,
                            const float* __restrict__ gamma,
                            const float* __restrict__ beta,
                            float* __restrict__ ab) {
    int f = threadIdx.x;
    if (f < 128) {
        float mean = stats[f] * (1.0f / N_NODES);
        float var = stats[128 + f] * (1.0f / N_NODES) - mean * mean;
        float rstd = rsqrtf(var + BN_EPS);
        float a = gamma[f] * rstd;
        float c = beta[f] - mean * a;
        ab[f] = a;
        ab[128 + f] = c;
    }
}

__global__ __launch_bounds__(256) void fused_gather_gemm1_f32(
    const float* __restrict__ xv,
    const int* __restrict__ rowptr,
    const int* __restrict__ ssrc,
    const unsigned short* __restrict__ Wb,
    const float* __restrict__ b1,
    float* __restrict__ hout,
    float* __restrict__ stats) {
    __shared__ unsigned short At[G_ROWS][AP];
    __shared__ float Ht[G_ROWS][HP];

    int t = threadIdx.x;
    int wave = t >> 6, lane = t & 63;
    int base = blockIdx.x * G_ROWS;
    int nrows = N_NODES - base; if (nrows > G_ROWS) nrows = G_ROWS;

    const float2* xf2 = (const float2*)xv;

    for (int nn = 0; nn < 8; nn++) {
        int r = wave * 8 + nn;
        int node = base + r;
        float2 acc = make_float2(0.f, 0.f);
        if (node < N_NODES) {
            acc = xf2[(size_t)node * 64 + lane];
            int beg = rowptr[node], end = rowptr[node + 1];
            for (int e = beg; e < end; e++) {
                float2 v0 = xf2[(size_t)ssrc[e] * 64 + lane];
                acc.x += v0.x;
                acc.y += v0.y;
            }
        }
        unsigned int packed = ((unsigned int)f2bf(acc.y) << 16) | (unsigned int)f2bf(acc.x);
        *((unsigned int*)&At[r][lane * 2]) = packed;
    }
    __syncthreads();

    int m0 = (wave & 1) * 16;
    int n0 = (wave >> 1) * 64;
    int l15 = lane & 15, q = lane >> 4;

    f32x4 acc[4];
#pragma unroll
    for (int i = 0; i < 4; i++) acc[i] = (f32x4){0.f, 0.f, 0.f, 0.f};

#pragma unroll
    for (int kc = 0; kc < 4; kc++) {
        short8 a = *((const short8*)&At[m0 + l15][kc * 32 + q * 8]);
#pragma unroll
        for (int tile = 0; tile < 4; tile++) {
            short8 b = *((const short8*)(Wb + (size_t)(n0 + 16 * tile + l15) * 128 + kc * 32 + q * 8));
            acc[tile] = __builtin_amdgcn_mfma_f32_16x16x32_bf16(a, b, acc[tile], 0, 0, 0);
        }
    }

#pragma unroll
    for (int tile = 0; tile < 4; tile++) {
        int col = n0 + 16 * tile + l15;
        float bias = b1[col];
#pragma unroll
        for (int reg = 0; reg < 4; reg++) {
            int row = q * 4 + reg;
            Ht[m0 + row][col] = fmaxf(acc[tile][reg] + bias, 0.f);
        }
    }
    __syncthreads();

    for (int i = t; i < G_ROWS * 32; i += 256) {
        int r = i >> 5, c4 = i & 31;
        int row = base + r;
        if (row < N_NODES)
            *((float4*)(hout + (size_t)row * NF + c4 * 4)) = *((const float4*)&Ht[r][c4 * 4]);
    }

    if (t < 128) {
        float s = 0.f, sq = 0.f;
        for (int r = 0; r < nrows; r++) {
            float v = Ht[r][t];
            s += v; sq += v * v;
        }
        atomicAdd(&stats[t], s);
        atomicAdd(&stats[128 + t], sq);
    }
}

__global__ __launch_bounds__(256) void gemm2_f32(
    float* __restrict__ h,
    const unsigned short* __restrict__ Wb,
    const float* __restrict__ b2,
    const float* __restrict__ ab) {
    __shared__ unsigned short At[G_ROWS][AP];
    __shared__ float Ht[G_ROWS][HP];

    int t = threadIdx.x;
    int base = blockIdx.x * G_ROWS;
    int nrows = N_NODES - base; if (nrows > G_ROWS) nrows = G_ROWS;

    for (int i = t; i < G_ROWS * 32; i += 256) {
        int r = i >> 5, c4 = i & 31;
        float4 v = make_float4(0.f, 0.f, 0.f, 0.f);
        if (r < nrows) {
            float4 hv = ((const float4*)(h + (size_t)(base + r) * NF))[c4];
            float4 av = ((const float4*)ab)[c4];
            float4 cv = ((const float4*)(ab + 128))[c4];
            v.x = hv.x * av.x + cv.x;
            v.y = hv.y * av.y + cv.y;
            v.z = hv.z * av.z + cv.z;
            v.w = hv.w * av.w + cv.w;
        }
        ushort4 u;
        u.x = f2bf(v.x); u.y = f2bf(v.y); u.z = f2bf(v.z); u.w = f2bf(v.w);
        *((ushort4*)&At[r][c4 * 4]) = u;
    }
    __syncthreads();

    int wave = t >> 6, lane = t & 63;
    int m0 = (wave & 1) * 16;
    int n0 = (wave >> 1) * 64;
    int l15 = lane & 15, q = lane >> 4;

    f32x4 acc[4];
#pragma unroll
    for (int i = 0; i < 4; i++) acc[i] = (f32x4){0.f, 0.f, 0.f, 0.f};

#pragma unroll
    for (int kc = 0; kc < 4; kc++) {
        short8 a = *((const short8*)&At[m0 + l15][kc * 32 + q * 8]);
#pragma unroll
        for (int tile = 0; tile < 4; tile++) {
            short8 b = *((const short8*)(Wb + (size_t)(n0 + 16 * tile + l15) * 128 + kc * 32 + q * 8));
            acc[tile] = __builtin_amdgcn_mfma_f32_16x16x32_bf16(a, b, acc[tile], 0, 0, 0);
        }
    }

#pragma unroll
    for (int tile = 0; tile < 4; tile++) {
        int col = n0 + 16 * tile + l15;
        float bias = b2[col];
#pragma unroll
        for (int reg = 0; reg < 4; reg++) {
            int row = q * 4 + reg;
            Ht[m0 + row][col] = acc[tile][reg] + bias;
        }
    }
    __syncthreads();

    for (int i = t; i < G_ROWS * 32; i += 256) {
        int r = i >> 5, c4 = i & 31;
        int row = base + r;
        if (row < N_NODES)
            *((float4*)(h + (size_t)row * NF + c4 * 4)) = *((const float4*)&Ht[r][c4 * 4]);
    }
}

extern "C" void kernel_launch(void* const* d_in, const int* in_sizes, int n_in,
                              void* d_out, int out_size, void* d_ws, size_t ws_size,
                              hipStream_t stream) {
    const float* x     = (const float*)d_in[0];
    const int*   ei    = (const int*)d_in[1];
    const float* W1    = (const float*)d_in[2];
    const float* b1    = (const float*)d_in[3];
    const float* gamma = (const float*)d_in[4];
    const float* beta  = (const float*)d_in[5];
    const float* W2    = (const float*)d_in[6];
    const float* b2    = (const float*)d_in[7];

    float* out = (float*)d_out;

    // Workspace layout
    float*          stats    = (float*)d_ws;                // 256 f (fallback)
    float*          ab       = stats + 256;                 // 256 f
    float*          P        = ab + 256;                    // 256*NB f (~1.6 MB)
    unsigned short* Wb1      = (unsigned short*)(P + 256 * NB); // 16384 us
    unsigned short* Wb2      = Wb1 + 128 * 128;             // 16384 us
    int*            counts   = (int*)(Wb2 + 128 * 128);     // 50000 i
    int*            rowptr   = counts + N_NODES;            // 50001 i
    int*            partials = rowptr + N_NODES + 1;        // 256 i (+pad)
    int*            rank     = partials + 256;              // 800000 i
    int*            ssrc     = rank + N_EDGES;              // 800000 i
    unsigned short* xb       = (unsigned short*)(ssrc + N_EDGES);   // 6.4M us
    unsigned short* buf      = xb + (size_t)N_NODES * NF;           // 6.4M us

    size_t need = (size_t)((char*)(buf + (size_t)N_NODES * NF) - (char*)d_ws);
    bool bf16_path = ws_size >= need;

    if (bf16_path) {
        int total = SETUP_C + SETUP_P + N_NODES + 256;
        setup_kernel<<<(total + 255) / 256, 256, 0, stream>>>(
            x, xb, W1, W2, Wb1, Wb2, counts, stats, 1);
    } else {
        int total = SETUP_P + N_NODES + 256;
        setup_kernel<<<(total + 255) / 256, 256, 0, stream>>>(
            x, xb, W1, W2, Wb1, Wb2, counts, stats, 0);
    }
    hist_kernel<<<(N_EDGES + 255) / 256, 256, 0, stream>>>(ei, counts, rank);
    scan_reduce<<<SCAN_BLOCKS, 256, 0, stream>>>(counts, partials);
    scan_apply<<<SCAN_BLOCKS, 256, 0, stream>>>(counts, partials, rowptr);
    fill_kernel<<<(N_EDGES + 255) / 256, 256, 0, stream>>>(ei, rowptr, rank, ssrc);

    if (bf16_path) {
        gather_bf16<<<(N_NODES * 64) / 256, 256, 0, stream>>>(xb, rowptr, ssrc, buf);
        gemm1_bf16<<<GBLOCKS, 256, 0, stream>>>(buf, Wb1, b1, P);
        bn_reduce<<<128, 256, 0, stream>>>(P, gamma, beta, ab);
        gemm2_bf16<<<GBLOCKS, 256, 0, stream>>>(buf, Wb2, b2, ab, out);
    } else {
        fused_gather_gemm1_f32<<<GBLOCKS, 256, 0, stream>>>(
            x, rowptr, ssrc, Wb1, b1, out, stats);
        finalize_bn<<<1, 128, 0, stream>>>(stats, gamma, beta, ab);
        gemm2_f32<<<GBLOCKS, 256, 0, stream>>>(out, Wb2, b2, ab);
    }
}